// Round 1
// baseline (105.035 us; speedup 1.0000x reference)
//
#include <hip/hip_runtime.h>

#define NPARTS 16
#define NIN 4
#define NH 16
#define NO 3
#define NEG_SLOPE 0.01f
#define BN_EPS 1e-5f
#define NN 64
#define NF 512
#define NF4 (NF / 4)   // 128 float4 groups per row
#define IPB 2          // batch items per block (k-outer, batch-inner reuse)

typedef float f32x4 __attribute__((ext_vector_type(4)));
union F4u { float4 f; f32x4 v; };

__device__ __forceinline__ float4 ntload4(const float4* p) {
    F4u u;
    u.v = __builtin_nontemporal_load(reinterpret_cast<const f32x4*>(p));
    return u.f;
}
__device__ __forceinline__ void ntstore4(float4* p, float4 x) {
    F4u u; u.f = x;
    __builtin_nontemporal_store(u.v, reinterpret_cast<f32x4*>(p));
}

// Branchless leaky ReLU: a>=0 -> a ; a<0 -> slope*a
__device__ __forceinline__ float leaky1(float a) {
    return fmaf(fminf(a, 0.0f), NEG_SLOPE - 1.0f, a);
}
__device__ __forceinline__ float4 leaky4(float4 a) {
    a.x = leaky1(a.x); a.y = leaky1(a.y); a.z = leaky1(a.z); a.w = leaky1(a.w);
    return a;
}
// d = v * s + d  (vector * broadcast-scalar accumulate)
__device__ __forceinline__ float4 fma4s(float4 v, float s, float4 d) {
    d.x = fmaf(v.x, s, d.x); d.y = fmaf(v.y, s, d.y);
    d.z = fmaf(v.z, s, d.z); d.w = fmaf(v.w, s, d.w);
    return d;
}
__device__ __forceinline__ float4 splat4(float s) {
    float4 r; r.x = s; r.y = s; r.z = s; r.w = s; return r;
}

// One block per (batch pair bi0..bi0+1, part p); 128 threads = one float4 group.
// x-row indices come from a wave-uniform int4 broadcast load (no LDS/barrier on
// the x-address path); all 8 x loads issue before weight staging so HBM latency
// overlaps the staging + barrier. Weights packed per hidden unit k as
// {W1[0..3][k], W2'[k][0..2], b1[k]} -> 2x ds_read_b128 per k, reused for IPB
// batch items. BN folded: y = h.(W2*sc) + ((b2-mean)*sc + beta).
__global__ __launch_bounds__(128)
void agg_joint_kernel(const float* __restrict__ x,
                      const int* __restrict__ parts,
                      const float* __restrict__ W1,
                      const float* __restrict__ b1,
                      const float* __restrict__ W2,
                      const float* __restrict__ b2,
                      const float* __restrict__ gamma,
                      const float* __restrict__ beta,
                      const float* __restrict__ mean,
                      const float* __restrict__ var,
                      float* __restrict__ out)
{
    const int p   = blockIdx.x & (NPARTS - 1);
    const int bi0 = (blockIdx.x >> 4) * IPB;
    const int t   = threadIdx.x;   // fi4 group index, 0..127

    // Wave-uniform 16 B broadcast load of the 4 source-row indices for part p.
    const int4 nidx = *reinterpret_cast<const int4*>(parts + p * NIN);

    // Issue all x loads up front: 16 B/lane fully-coalesced, non-temporal
    // (each row is consumed exactly once; L3 is wiped by the harness anyway).
    float4 xv[IPB][NIN];
    const float4* xf = reinterpret_cast<const float4*>(x);
#pragma unroll
    for (int i = 0; i < IPB; ++i) {
        const size_t rb = (size_t)(bi0 + i) * NN;
        xv[i][0] = ntload4(xf + (rb + (size_t)nidx.x) * NF4 + t);
        xv[i][1] = ntload4(xf + (rb + (size_t)nidx.y) * NF4 + t);
        xv[i][2] = ntload4(xf + (rb + (size_t)nidx.z) * NF4 + t);
        xv[i][3] = ntload4(xf + (rb + (size_t)nidx.w) * NF4 + t);
    }

    // Packed per-k record: [k][0..3] = W1 column, [4..6] = BN-scaled W2 row,
    // [7] = b1[k]. 128 floats total -> one float per thread.
    __shared__ __align__(16) float s_pack[NH][8];
    __shared__ float s_shift[NO];
    {
        const int k   = t >> 3;
        const int idx = t & 7;
        float wv;
        if (idx < NIN) {
            wv = W1[(p * NIN + idx) * NH + k];
        } else if (idx < 7) {
            const int o = idx - NIN;
            wv = W2[(p * NH + k) * NO + o] *
                 (gamma[p * NO + o] * rsqrtf(var[p * NO + o] + BN_EPS));
        } else {
            wv = b1[p * NH + k];
        }
        s_pack[k][idx] = wv;
        if (t < NO) {
            const float sc = gamma[p * NO + t] * rsqrtf(var[p * NO + t] + BN_EPS);
            s_shift[t] = (b2[p * NO + t] - mean[p * NO + t]) * sc + beta[p * NO + t];
        }
    }
    __syncthreads();

    float4 acc[IPB][NO];
#pragma unroll
    for (int i = 0; i < IPB; ++i)
#pragma unroll
        for (int o = 0; o < NO; ++o) acc[i][o] = splat4(s_shift[o]);

    // Hidden loop: 2x ds_read_b128 per k, reused across both batch items.
#pragma unroll
    for (int k = 0; k < NH; ++k) {
        const float4 wa = *reinterpret_cast<const float4*>(&s_pack[k][0]);
        const float4 wb = *reinterpret_cast<const float4*>(&s_pack[k][4]);
#pragma unroll
        for (int i = 0; i < IPB; ++i) {
            float4 h = splat4(wb.w);
            h = fma4s(xv[i][0], wa.x, h);
            h = fma4s(xv[i][1], wa.y, h);
            h = fma4s(xv[i][2], wa.z, h);
            h = fma4s(xv[i][3], wa.w, h);
            h = leaky4(h);
            acc[i][0] = fma4s(h, wb.x, acc[i][0]);
            acc[i][1] = fma4s(h, wb.y, acc[i][1]);
            acc[i][2] = fma4s(h, wb.z, acc[i][2]);
        }
    }

    // Final leaky ReLU + coalesced non-temporal float4 stores.
    float4* of = reinterpret_cast<float4*>(out);
#pragma unroll
    for (int i = 0; i < IPB; ++i) {
        float4* ob = of + ((size_t)(bi0 + i) * (NPARTS * NO) + p * NO) * NF4 + t;
#pragma unroll
        for (int o = 0; o < NO; ++o)
            ntstore4(ob + (size_t)o * NF4, leaky4(acc[i][o]));
    }
}

extern "C" void kernel_launch(void* const* d_in, const int* in_sizes, int n_in,
                              void* d_out, int out_size, void* d_ws, size_t ws_size,
                              hipStream_t stream) {
    const float* x     = (const float*)d_in[0];
    const int*   parts = (const int*)d_in[1];
    const float* W1    = (const float*)d_in[2];
    const float* b1    = (const float*)d_in[3];
    const float* W2    = (const float*)d_in[4];
    const float* b2    = (const float*)d_in[5];
    const float* gamma = (const float*)d_in[6];
    const float* beta  = (const float*)d_in[7];
    const float* mean  = (const float*)d_in[8];
    const float* var   = (const float*)d_in[9];
    float* out = (float*)d_out;

    const int batch = in_sizes[0] / (NN * NF);   // 256
    dim3 grid((batch / IPB) * NPARTS);           // 2048 blocks
    dim3 block(128);
    agg_joint_kernel<<<grid, block, 0, stream>>>(
        x, parts, W1, b1, W2, b2, gamma, beta, mean, var, out);
}

// Round 2
// 100.933 us; speedup vs baseline: 1.0406x; 1.0406x over previous
//
#include <hip/hip_runtime.h>

#define NPARTS 16
#define NIN 4
#define NH 16
#define NO 3
#define NEG_SLOPE 0.01f
#define BN_EPS 1e-5f
#define NN 64
#define NF 512
#define NF4 (NF / 4)   // 128 float4 groups per row

// Branchless leaky ReLU: a>=0 -> a ; a<0 -> slope*a
__device__ __forceinline__ float leaky1(float a) {
    return fmaf(fminf(a, 0.0f), NEG_SLOPE - 1.0f, a);
}
__device__ __forceinline__ float4 leaky4(float4 a) {
    a.x = leaky1(a.x); a.y = leaky1(a.y); a.z = leaky1(a.z); a.w = leaky1(a.w);
    return a;
}
// d = v * s + d  (vector * broadcast-scalar accumulate)
__device__ __forceinline__ float4 fma4s(float4 v, float s, float4 d) {
    d.x = fmaf(v.x, s, d.x); d.y = fmaf(v.y, s, d.y);
    d.z = fmaf(v.z, s, d.z); d.w = fmaf(v.w, s, d.w);
    return d;
}
__device__ __forceinline__ float4 splat4(float s) {
    float4 r; r.x = s; r.y = s; r.z = s; r.w = s; return r;
}

// One block per (batch bi, part p); 128 threads = one float4 group of fi each.
// Round-0 geometry (4096 blocks, measured 100.3 us) + two clean improvements:
//  - x-row indices via wave-uniform int4 broadcast (s_load_dwordx4): no LDS or
//    barrier on the x-address critical path; the 4 coalesced 16 B/lane x loads
//    issue immediately and their HBM latency overlaps weight staging + barrier.
//  - weights packed per hidden unit k as {W1[0..3][k], W2'[k][0..2], b1[k]}:
//    inner loop does 2x ds_read_b128 per k instead of 8x ds_read_b32.
// Plain cached loads/stores (round-1 nontemporal hints regressed ~5 us:
// nt write-around loses L2 write combining on the 25 MB output stream).
// BN folded: y = h.(W2*sc) + ((b2-mean)*sc + beta), sc = gamma*rsqrt(var+eps).
__global__ __launch_bounds__(128)
void agg_joint_kernel(const float* __restrict__ x,
                      const int* __restrict__ parts,
                      const float* __restrict__ W1,
                      const float* __restrict__ b1,
                      const float* __restrict__ W2,
                      const float* __restrict__ b2,
                      const float* __restrict__ gamma,
                      const float* __restrict__ beta,
                      const float* __restrict__ mean,
                      const float* __restrict__ var,
                      float* __restrict__ out)
{
    const int p  = blockIdx.x & (NPARTS - 1);
    const int bi = blockIdx.x >> 4;
    const int t  = threadIdx.x;   // fi4 group index, 0..127

    // Wave-uniform 16 B broadcast load of the 4 source-row indices for part p.
    const int4 nidx = *reinterpret_cast<const int4*>(parts + p * NIN);

    // Issue all 4 x loads up front: 16 B/lane fully-coalesced.
    const float4* xf = reinterpret_cast<const float4*>(x);
    const size_t rb = (size_t)bi * NN;
    float4 xv0 = xf[(rb + (size_t)nidx.x) * NF4 + t];
    float4 xv1 = xf[(rb + (size_t)nidx.y) * NF4 + t];
    float4 xv2 = xf[(rb + (size_t)nidx.z) * NF4 + t];
    float4 xv3 = xf[(rb + (size_t)nidx.w) * NF4 + t];

    // Packed per-k record: [k][0..3] = W1 column, [4..6] = BN-scaled W2 row,
    // [7] = b1[k]. 128 floats total -> one float per thread.
    __shared__ __align__(16) float s_pack[NH][8];
    __shared__ float s_shift[NO];
    {
        const int k   = t >> 3;
        const int idx = t & 7;
        float wv;
        if (idx < NIN) {
            wv = W1[(p * NIN + idx) * NH + k];
        } else if (idx < 7) {
            const int o = idx - NIN;
            wv = W2[(p * NH + k) * NO + o] *
                 (gamma[p * NO + o] * rsqrtf(var[p * NO + o] + BN_EPS));
        } else {
            wv = b1[p * NH + k];
        }
        s_pack[k][idx] = wv;
        if (t < NO) {
            const float sc = gamma[p * NO + t] * rsqrtf(var[p * NO + t] + BN_EPS);
            s_shift[t] = (b2[p * NO + t] - mean[p * NO + t]) * sc + beta[p * NO + t];
        }
    }
    __syncthreads();

    // Output accumulators initialized with the folded BN shift.
    float4 acc0 = splat4(s_shift[0]);
    float4 acc1 = splat4(s_shift[1]);
    float4 acc2 = splat4(s_shift[2]);

    // Hidden loop: 2x ds_read_b128 per k.
#pragma unroll
    for (int k = 0; k < NH; ++k) {
        const float4 wa = *reinterpret_cast<const float4*>(&s_pack[k][0]);
        const float4 wb = *reinterpret_cast<const float4*>(&s_pack[k][4]);
        float4 h = splat4(wb.w);
        h = fma4s(xv0, wa.x, h);
        h = fma4s(xv1, wa.y, h);
        h = fma4s(xv2, wa.z, h);
        h = fma4s(xv3, wa.w, h);
        h = leaky4(h);
        acc0 = fma4s(h, wb.x, acc0);
        acc1 = fma4s(h, wb.y, acc1);
        acc2 = fma4s(h, wb.z, acc2);
    }

    // Final leaky ReLU + coalesced float4 stores.
    float4* ob = reinterpret_cast<float4*>(out) +
                 ((size_t)bi * (NPARTS * NO) + p * NO) * NF4 + t;
    ob[0]            = leaky4(acc0);
    ob[(size_t)NF4]  = leaky4(acc1);
    ob[(size_t)2 * NF4] = leaky4(acc2);
}

extern "C" void kernel_launch(void* const* d_in, const int* in_sizes, int n_in,
                              void* d_out, int out_size, void* d_ws, size_t ws_size,
                              hipStream_t stream) {
    const float* x     = (const float*)d_in[0];
    const int*   parts = (const int*)d_in[1];
    const float* W1    = (const float*)d_in[2];
    const float* b1    = (const float*)d_in[3];
    const float* W2    = (const float*)d_in[4];
    const float* b2    = (const float*)d_in[5];
    const float* gamma = (const float*)d_in[6];
    const float* beta  = (const float*)d_in[7];
    const float* mean  = (const float*)d_in[8];
    const float* var   = (const float*)d_in[9];
    float* out = (float*)d_out;

    const int batch = in_sizes[0] / (NN * NF);   // 256
    dim3 grid(batch * NPARTS);                   // 4096 blocks
    dim3 block(128);
    agg_joint_kernel<<<grid, block, 0, stream>>>(
        x, parts, W1, b1, W2, b2, gamma, beta, mean, var, out);
}